// Round 1
// 785.320 us; speedup vs baseline: 1.0129x; 1.0129x over previous
//
#include <hip/hip_runtime.h>
#include <math.h>

// Problem constants: B=512, T=256, F=D=1024, all fp32.
// Algebraic restructure:
//   q   = z @ Wq^T + bq                      [512,1024]   (GEMM BT, bias)
//   qk  = q @ Wk                             [512,1024]   (GEMM BN)     -- bk drops (softmax-invariant)
//   scores[b,t] = past[b,t,:] . qk[b,:]      streaming, online softmax (split-T, wave-autonomous)
//   ctxf[b,f]   = sum_t w[b,t] past[b,t,f]   same streaming pass (past read ONCE)
//   out = ctxf @ Wv^T + bv                   [512,1024]   (GEMM BT, bias in add kernel)

#define MM 512
#define NN 1024
#define KK 1024
#define NPART 4          // split-K partials for all GEMMs
#define KCHUNK (KK / NPART)

// ---------------- fp32 tiled GEMM, 64x64 tile, TK=16, 4x4 micro, split-K=NPART
// C is [NPART][512][1024] partials (kz = blockIdx.z). BT=1: Bm is [N,K].
// SUMA=1: A is [NPART][512][1024] partials, summed on load. BIAS applied at kz==0.
template<int BT, int SUMA, int BIAS>
__global__ __launch_bounds__(256) void gemm_f32(const float* __restrict__ A,
        const float* __restrict__ Bm, const float* __restrict__ bias,
        float* __restrict__ C)
{
    __shared__ float As[16][68];
    __shared__ float Bs[16][68];
    const int tid = threadIdx.x;
    const int tx = tid & 15, ty = tid >> 4;
    const int n0 = blockIdx.x * 64, m0 = blockIdx.y * 64, kz = blockIdx.z;
    const int kbeg = kz * KCHUNK;
    const int arow = tid >> 2, akq = tid & 3;   // 64 rows x 4 float4 along K

    float c[4][4] = {};

    for (int kt = 0; kt < KCHUNK; kt += 16) {
        const int k0 = kbeg + kt;
        // A tile -> As[k][m] (transposed scatter; 2-way bank alias = free)
        {
            const float* ap = A + (size_t)(m0 + arow) * KK + k0 + akq * 4;
            float4 a = *(const float4*)ap;
            if (SUMA) {
                #pragma unroll
                for (int p = 1; p < NPART; ++p) {
                    float4 a2 = *(const float4*)(ap + (size_t)p * MM * NN);
                    a.x += a2.x; a.y += a2.y; a.z += a2.z; a.w += a2.w;
                }
            }
            As[akq*4+0][arow] = a.x; As[akq*4+1][arow] = a.y;
            As[akq*4+2][arow] = a.z; As[akq*4+3][arow] = a.w;
        }
        if (BT) {  // Bm[N,K]: Bs[k][n] = Bm[n0+n][k0+k]
            const float* bp = Bm + (size_t)(n0 + arow) * KK + k0 + akq * 4;
            float4 b = *(const float4*)bp;
            Bs[akq*4+0][arow] = b.x; Bs[akq*4+1][arow] = b.y;
            Bs[akq*4+2][arow] = b.z; Bs[akq*4+3][arow] = b.w;
        } else {   // Bm[K,N]: direct row copy
            const int krow = tid >> 4, nq = tid & 15;
            float4 b = *(const float4*)(Bm + (size_t)(k0 + krow) * NN + n0 + nq * 4);
            *(float4*)&Bs[krow][nq * 4] = b;
        }
        __syncthreads();
        #pragma unroll
        for (int k = 0; k < 16; ++k) {
            float4 a4 = *(const float4*)&As[k][ty * 4];
            float4 b4 = *(const float4*)&Bs[k][tx * 4];
            float av[4] = {a4.x, a4.y, a4.z, a4.w};
            float bw[4] = {b4.x, b4.y, b4.z, b4.w};
            #pragma unroll
            for (int i = 0; i < 4; ++i)
                #pragma unroll
                for (int j = 0; j < 4; ++j)
                    c[i][j] = fmaf(av[i], bw[j], c[i][j]);
        }
        __syncthreads();
    }

    float* Cp = C + (size_t)kz * MM * NN;
    #pragma unroll
    for (int i = 0; i < 4; ++i) {
        const int m = m0 + ty * 4 + i;
        const int n = n0 + tx * 4;
        float4 o = make_float4(c[i][0], c[i][1], c[i][2], c[i][3]);
        if (BIAS && kz == 0) {
            o.x += bias[n]; o.y += bias[n+1]; o.z += bias[n+2]; o.w += bias[n+3];
        }
        *(float4*)&Cp[(size_t)m * NN + n] = o;
    }
}

// ---------------- streaming attention, split-T, wave-autonomous ---------------
// grid = 2048 blocks (512 b x 4 chunks), 256 threads = 4 independent waves.
// Wave (b, widx) handles rows t in [widx*16, widx*16+16). Lane owns 16 f-cols
// (f = q*256 + lane*4, q=0..3). No __syncthreads, no LDS in the hot loop.
// Per row: 4 coalesced float4 loads, 16-FMA dot, 6-step shfl_xor butterfly
// (result broadcast to all lanes), defer-max online softmax, 16-FMA accumulate.
#define TW 16

__global__ __launch_bounds__(256) void attn_part(const float* __restrict__ past,
        const float* __restrict__ qk2, float* __restrict__ pacc,
        float2* __restrict__ pml)
{
    const int bid = blockIdx.x;
    const int b = bid >> 2, c = bid & 3;
    const int lane = threadIdx.x & 63, w = threadIdx.x >> 6;
    const int widx = (c << 2) | w;
    const int t0 = widx * TW;

    // qk[b, f] for this lane's 16 columns (sum NPART split-K partials)
    float4 qk[4];
    #pragma unroll
    for (int q = 0; q < 4; ++q) {
        const float* qp = qk2 + (size_t)b * NN + q * 256 + lane * 4;
        float4 v = *(const float4*)qp;
        #pragma unroll
        for (int p = 1; p < NPART; ++p) {
            float4 v2 = *(const float4*)(qp + (size_t)p * MM * NN);
            v.x += v2.x; v.y += v2.y; v.z += v2.z; v.w += v2.w;
        }
        qk[q] = v;
    }

    const float* base = past + ((size_t)b * 256 + t0) * NN + lane * 4;
    float m = -INFINITY, l = 0.f;
    float4 acc[4] = {};

    float4 r[4], rn[4];
    #pragma unroll
    for (int q = 0; q < 4; ++q) r[q] = *(const float4*)(base + q * 256);

    #pragma unroll 2
    for (int t = 0; t < TW; ++t) {
        if (t + 1 < TW) {   // prefetch next row (4 in-flight 1KB loads/wave)
            #pragma unroll
            for (int q = 0; q < 4; ++q)
                rn[q] = *(const float4*)(base + (size_t)(t + 1) * NN + q * 256);
        }
        const float d0 = r[0].x*qk[0].x + r[0].y*qk[0].y + r[0].z*qk[0].z + r[0].w*qk[0].w;
        const float d1 = r[1].x*qk[1].x + r[1].y*qk[1].y + r[1].z*qk[1].z + r[1].w*qk[1].w;
        const float d2 = r[2].x*qk[2].x + r[2].y*qk[2].y + r[2].z*qk[2].z + r[2].w*qk[2].w;
        const float d3 = r[3].x*qk[3].x + r[3].y*qk[3].y + r[3].z*qk[3].z + r[3].w*qk[3].w;
        float p = (d0 + d1) + (d2 + d3);
        #pragma unroll
        for (int off = 1; off < 64; off <<= 1)
            p += __shfl_xor(p, off, 64);
        // p now identical (bitwise) on all 64 lanes -> wave-uniform control flow.
        float dd = p - m;
        if (dd > 8.f) {            // defer-max: rescale only on big max growth
            const float alpha = __expf(-dd);   // first row: exp(-inf) = 0
            l *= alpha;
            #pragma unroll
            for (int q = 0; q < 4; ++q) {
                acc[q].x *= alpha; acc[q].y *= alpha;
                acc[q].z *= alpha; acc[q].w *= alpha;
            }
            m = p; dd = 0.f;
        }
        const float pe = __expf(dd);           // bounded by e^8
        l += pe;
        #pragma unroll
        for (int q = 0; q < 4; ++q) {
            acc[q].x = fmaf(pe, r[q].x, acc[q].x);
            acc[q].y = fmaf(pe, r[q].y, acc[q].y);
            acc[q].z = fmaf(pe, r[q].z, acc[q].z);
            acc[q].w = fmaf(pe, r[q].w, acc[q].w);
        }
        #pragma unroll
        for (int q = 0; q < 4; ++q) r[q] = rn[q];
    }

    float* pa = pacc + ((size_t)b * 16 + widx) * NN + lane * 4;
    #pragma unroll
    for (int q = 0; q < 4; ++q) *(float4*)(pa + q * 256) = acc[q];
    if (lane == 0) pml[b * 16 + widx] = make_float2(m, l);
}

// ---------------- combine 16 per-wave partials per b --------------------------
__global__ __launch_bounds__(256) void attn_combine(const float* __restrict__ pacc,
        const float2* __restrict__ pml, float* __restrict__ ctx)
{
    const int b = blockIdx.x;
    const int e = threadIdx.x;           // owns 4 cols: f = e*4
    __shared__ float sm[16], sl[16];
    if (e < 16) {
        float2 v = pml[b * 16 + e];
        sm[e] = v.x; sl[e] = v.y;
    }
    __syncthreads();
    float M = sm[0];
    #pragma unroll
    for (int i = 1; i < 16; ++i) M = fmaxf(M, sm[i]);
    float L = 0.f, wgt[16];
    #pragma unroll
    for (int i = 0; i < 16; ++i) {
        wgt[i] = __expf(sm[i] - M);
        L = fmaf(sl[i], wgt[i], L);
    }
    const float inv = 1.f / L;
    const float* pa = pacc + (size_t)b * 16 * NN + e * 4;
    float4 o = {};
    #pragma unroll
    for (int i = 0; i < 16; ++i) {
        float4 a = *(const float4*)(pa + (size_t)i * NN);
        o.x = fmaf(wgt[i], a.x, o.x);
        o.y = fmaf(wgt[i], a.y, o.y);
        o.z = fmaf(wgt[i], a.z, o.z);
        o.w = fmaf(wgt[i], a.w, o.w);
    }
    o.x *= inv; o.y *= inv; o.z *= inv; o.w *= inv;
    *(float4*)(ctx + (size_t)b * NN + e * 4) = o;
}

// ---------------- final: out = sum_p o2[p] + bv -------------------------------
__global__ __launch_bounds__(256) void add_bias_out(const float* __restrict__ o2,
        const float* __restrict__ bv, float* __restrict__ out)
{
    const int i = (blockIdx.x * 256 + threadIdx.x) * 4;   // over 512*1024
    float4 a = *(const float4*)(o2 + i);
    #pragma unroll
    for (int p = 1; p < NPART; ++p) {
        float4 b = *(const float4*)(o2 + (size_t)p * MM * NN + i);
        a.x += b.x; a.y += b.y; a.z += b.z; a.w += b.w;
    }
    const int n = i & 1023;
    float4 bb = *(const float4*)(bv + n);
    float4 rr = make_float4(a.x + bb.x, a.y + bb.y, a.z + bb.z, a.w + bb.w);
    *(float4*)(out + i) = rr;
}

extern "C" void kernel_launch(void* const* d_in, const int* in_sizes, int n_in,
                              void* d_out, int out_size, void* d_ws, size_t ws_size,
                              hipStream_t stream) {
    const float* z    = (const float*)d_in[0];
    const float* past = (const float*)d_in[1];
    const float* Wq   = (const float*)d_in[2];
    const float* Wk   = (const float*)d_in[3];
    const float* Wv   = (const float*)d_in[4];
    const float* bq   = (const float*)d_in[5];
    // d_in[6] = bk: constant over t in scores -> softmax-invariant, unused.
    const float* bv   = (const float*)d_in[7];
    float* out = (float*)d_out;

    // workspace layout (floats):
    //   q2  [NPART*512*1024]  (8 MB)   -- reused as o2 after GEMM2
    //   qk2 [NPART*512*1024]  (8 MB)
    //   ctx [512*1024]        (2 MB)
    //   pacc[512*16*1024]     (32 MB)
    //   pml [512*16] float2   (64 KB)
    float* q2   = (float*)d_ws;
    float* qk2  = q2 + (size_t)NPART * MM * NN;
    float* ctx  = qk2 + (size_t)NPART * MM * NN;
    float* pacc = ctx + (size_t)MM * NN;
    float2* pml = (float2*)(pacc + (size_t)512 * 16 * 1024);
    float* o2   = q2;   // q2 dead after GEMM2

    dim3 g(NN / 64, MM / 64, NPART), blk(256);
    gemm_f32<1, 0, 1><<<g, blk, 0, stream>>>(z,   Wq, bq,      q2);   // q  = z @ Wq^T + bq
    gemm_f32<0, 1, 0><<<g, blk, 0, stream>>>(q2,  Wk, nullptr, qk2);  // qk = q @ Wk
    attn_part<<<dim3(2048), blk, 0, stream>>>(past, qk2, pacc, pml);  // split-T online softmax
    attn_combine<<<dim3(512), blk, 0, stream>>>(pacc, pml, ctx);      // merge 16 partials/b
    gemm_f32<1, 0, 0><<<g, blk, 0, stream>>>(ctx, Wv, nullptr, o2);   // ctxf @ Wv^T
    add_bias_out<<<dim3(512), blk, 0, stream>>>(o2, bv, out);         // sum partials + bv
}